// Round 5
// baseline (5026.619 us; speedup 1.0000x reference)
//
#include <hip/hip_runtime.h>
#include <hip/hip_bf16.h>

// GPT forward, MI355X. B=4 T=2048 C=1024 H=16 DH=64 L=8 OUT=1024.
// bf16 MFMA (16x16x32) for all GEMMs + flash attention; fp32 residual stream.

#define LAYERS 8
#define NH 16
#define TT 2048
#define CC 1024
#define NB 4
#define MR (NB*TT)          // 8192 token rows
#define LN_EPS 1e-5f

typedef __bf16 bf16_t;
typedef __attribute__((ext_vector_type(8))) __bf16 bf16x8;
typedef __attribute__((ext_vector_type(4))) __bf16 bf16x4;
typedef __attribute__((ext_vector_type(4))) float f32x4;
typedef __attribute__((ext_vector_type(8))) short s16x8;

__device__ inline f32x4 mfma16x16x32(bf16x8 a, bf16x8 b, f32x4 c) {
    return __builtin_amdgcn_mfma_f32_16x16x32_bf16(a, b, c, 0, 0, 0);
}

__device__ inline void gload_lds16(const void* g, void* lds) {
    __builtin_amdgcn_global_load_lds((const __attribute__((address_space(1))) void*)g,
                                     (__attribute__((address_space(3))) void*)lds, 16, 0, 0);
}

// ---------------- elementwise helpers ----------------

__global__ __launch_bounds__(256) void add_pos_k(const float* __restrict__ s,
                                                 const float* __restrict__ p,
                                                 float* __restrict__ x) {
    int i = blockIdx.x * 256 + threadIdx.x;          // float4 units
    float4 a = ((const float4*)s)[i];
    float4 b = ((const float4*)p)[i & ((TT * CC / 4) - 1)];
    ((float4*)x)[i] = make_float4(a.x + b.x, a.y + b.y, a.z + b.z, a.w + b.w);
}

__global__ __launch_bounds__(256) void f32_to_bf16_k(const float* __restrict__ s,
                                                     bf16_t* __restrict__ d, int n4) {
    int i = blockIdx.x * 256 + threadIdx.x;
    if (i < n4) {
        float4 v = ((const float4*)s)[i];
        bf16x4 o;
        o[0] = (bf16_t)v.x; o[1] = (bf16_t)v.y; o[2] = (bf16_t)v.z; o[3] = (bf16_t)v.w;
        ((bf16x4*)d)[i] = o;
    }
}

// One launch per layer: convert Wq|Wk|Wv -> wqkvb, Wo -> wob, W1 -> w1b,
// W2 -> w2b (f32->bf16, float4-vectorized) and concat bq|bk|bv -> bqkv.
__global__ __launch_bounds__(256) void convert_layer_k(
        const float* __restrict__ Wq, const float* __restrict__ Wk,
        const float* __restrict__ Wv, const float* __restrict__ Wo,
        const float* __restrict__ W1, const float* __restrict__ W2,
        const float* __restrict__ bq, const float* __restrict__ bk,
        const float* __restrict__ bv,
        bf16_t* __restrict__ wqkvb, bf16_t* __restrict__ wob,
        bf16_t* __restrict__ w1b, bf16_t* __restrict__ w2b,
        float* __restrict__ bqkv) {
    const int i = blockIdx.x * 256 + threadIdx.x;    // float4 units
    if (i < 3145728) {
        const float4* s4;
        bf16_t* dst;
        int off;
        if (i < 262144)       { s4 = (const float4*)Wq + i;             dst = wqkvb; off = i; }
        else if (i < 524288)  { s4 = (const float4*)Wk + (i - 262144);  dst = wqkvb; off = i; }
        else if (i < 786432)  { s4 = (const float4*)Wv + (i - 524288);  dst = wqkvb; off = i; }
        else if (i < 1048576) { s4 = (const float4*)Wo + (i - 786432);  dst = wob;   off = i - 786432; }
        else if (i < 2097152) { s4 = (const float4*)W1 + (i - 1048576); dst = w1b;   off = i - 1048576; }
        else                  { s4 = (const float4*)W2 + (i - 2097152); dst = w2b;   off = i - 2097152; }
        float4 v = *s4;
        bf16x4 o;
        o[0] = (bf16_t)v.x; o[1] = (bf16_t)v.y; o[2] = (bf16_t)v.z; o[3] = (bf16_t)v.w;
        ((bf16x4*)dst)[off] = o;
    } else if (i < 3146496) {        // bias concat: 768 f4 = 3072 floats
        const int j = i - 3145728;
        const float* b = (j < 256) ? bq : (j < 512 ? bk : bv);
        ((float4*)bqkv)[j] = ((const float4*)b)[j & 255];
    }
}

// ---------------- LayerNorm: one wave per row, bf16 out ----------------

__global__ __launch_bounds__(256) void ln_rows_k(const float* __restrict__ x,
                                                 const float* __restrict__ wgt,
                                                 const float* __restrict__ bgt,
                                                 bf16_t* __restrict__ out) {
    const int row = blockIdx.x * 4 + (threadIdx.x >> 6);
    const int l = threadIdx.x & 63;
    const float* xr = x + (size_t)row * CC;
    float4 v[4];
    float s = 0.f, sq = 0.f;
#pragma unroll
    for (int j = 0; j < 4; j++) {
        v[j] = *(const float4*)&xr[j * 256 + l * 4];
        s  += v[j].x + v[j].y + v[j].z + v[j].w;
        sq += v[j].x * v[j].x + v[j].y * v[j].y + v[j].z * v[j].z + v[j].w * v[j].w;
    }
#pragma unroll
    for (int m = 1; m < 64; m <<= 1) { s += __shfl_xor(s, m); sq += __shfl_xor(sq, m); }
    const float mu = s * (1.f / CC);
    const float rstd = rsqrtf(sq * (1.f / CC) - mu * mu + LN_EPS);
#pragma unroll
    for (int j = 0; j < 4; j++) {
        const int c0 = j * 256 + l * 4;
        const float4 wv = *(const float4*)&wgt[c0];
        const float4 bv = *(const float4*)&bgt[c0];
        bf16x4 o;
        o[0] = (bf16_t)((v[j].x - mu) * rstd * wv.x + bv.x);
        o[1] = (bf16_t)((v[j].y - mu) * rstd * wv.y + bv.y);
        o[2] = (bf16_t)((v[j].z - mu) * rstd * wv.z + bv.z);
        o[3] = (bf16_t)((v[j].w - mu) * rstd * wv.w + bv.w);
        *(bf16x4*)&out[(size_t)row * CC + c0] = o;
    }
}

// ---------------- GEMM: C[M,N] = A[M,K] @ B[N,K]^T, m97 structure ----------------
// 128x128 tile, BK=32, 4 waves each 64x64 (4x4 of 16x16x32 MFMA), global_load_lds.
// 1D grid with XCD-aware swizzle (T1); all grids are %8==0 so the simple
// bijective form is valid.

#define EPI_BF16 0   // obf = acc + bias
#define EPI_GELU 1   // obf = gelu(acc + bias)
#define EPI_RES  2   // resid(fp32,[M][CC]) += acc + bias
#define EPI_F32  3   // of32 = acc (no bias)

template <int EPI>
__global__ __launch_bounds__(256) void gemm_bt(const bf16_t* __restrict__ A,
                                               const bf16_t* __restrict__ Bw,
                                               const float* __restrict__ bias,
                                               float* __restrict__ resid,
                                               bf16_t* __restrict__ obf,
                                               float* __restrict__ of32,
                                               int N, int K, int nbn) {
    __shared__ __align__(16) bf16_t As[128 * 32];
    __shared__ __align__(16) bf16_t Bs[128 * 32];
    const int nwg = gridDim.x;
    const int id = blockIdx.x;
    const int swz = (id & 7) * (nwg >> 3) + (id >> 3);
    const int bn = swz % nbn, bm = swz / nbn;
    const int t = threadIdx.x, w = t >> 6, l = t & 63;
    const int wm = (w >> 1) << 6, wn = (w & 1) << 6;
    const int fr = l & 15, fg = l >> 4;
    const int srow = l >> 2, scol = (l & 3) * 8;   // lane -> (row, 8-elem chunk), LDS-linear
    f32x4 acc[4][4] = {};
    for (int k0 = 0; k0 < K; k0 += 32) {
#pragma unroll
        for (int it = 0; it < 2; ++it) {
            const int rr = it * 64 + w * 16;
            gload_lds16(A  + (size_t)(bm * 128 + rr + srow) * K + k0 + scol, &As[rr * 32]);
            gload_lds16(Bw + (size_t)(bn * 128 + rr + srow) * K + k0 + scol, &Bs[rr * 32]);
        }
        __syncthreads();
        bf16x8 af[4], bfv[4];
#pragma unroll
        for (int i = 0; i < 4; i++) af[i]  = *(const bf16x8*)&As[(wm + i * 16 + fr) * 32 + fg * 8];
#pragma unroll
        for (int j = 0; j < 4; j++) bfv[j] = *(const bf16x8*)&Bs[(wn + j * 16 + fr) * 32 + fg * 8];
#pragma unroll
        for (int i = 0; i < 4; i++)
#pragma unroll
            for (int j = 0; j < 4; j++)
                acc[i][j] = mfma16x16x32(af[i], bfv[j], acc[i][j]);
        __syncthreads();
    }
    // C/D layout: col = lane&15, row = (lane>>4)*4 + reg  [m89-verified]
#pragma unroll
    for (int i = 0; i < 4; i++) {
#pragma unroll
        for (int j = 0; j < 4; j++) {
            const int col = bn * 128 + wn + j * 16 + fr;
            float bv = 0.f;
            if constexpr (EPI != EPI_F32) bv = bias[col];
#pragma unroll
            for (int rg = 0; rg < 4; ++rg) {
                const int row = bm * 128 + wm + i * 16 + fg * 4 + rg;
                float v = acc[i][j][rg] + bv;
                if constexpr (EPI == EPI_BF16) {
                    obf[(size_t)row * N + col] = (bf16_t)v;
                } else if constexpr (EPI == EPI_GELU) {
                    v = 0.5f * v * (1.0f + erff(v * 0.70710678118f));
                    obf[(size_t)row * N + col] = (bf16_t)v;
                } else if constexpr (EPI == EPI_RES) {
                    resid[(size_t)row * CC + col] += v;
                } else {
                    of32[(size_t)row * N + col] = v;
                }
            }
        }
    }
}

// ---------------- Flash attention ----------------
// qkv: [MR][3C] bf16 (q|k|v). Per block: one (b,h), 64 q-rows; 4 waves x 16 q-rows.
// KV tiles of 64. K staged swizzled row-major; V^T staged transposed with a
// two-term XOR swizzle (d&7 for read spread, d>>3 for write spread). Online
// softmax in exp2 domain with defer-max (T13). Next-tile global loads issued
// before compute (T14-lite). 2 barriers/tile.

__global__ __launch_bounds__(256, 2) void attn_k(const bf16_t* __restrict__ qkv,
                                                 bf16_t* __restrict__ y) {
    __shared__ __align__(16) bf16_t Ks[64 * 64];
    __shared__ __align__(16) bf16_t Vt[64 * 64];
    __shared__ __align__(16) bf16_t Ps[4 * 16 * 64];
    const int id = blockIdx.x;                    // 2048 blocks, %8==0
    const int swz = (id & 7) * 256 + (id >> 3);   // XCD swizzle: same bh -> same XCD
    const int qt = swz & 31, bh = swz >> 5;
    const int b = bh >> 4, h = bh & 15;
    const int t = threadIdx.x, w = t >> 6, l = t & 63;
    const int fr = l & 15, fg = l >> 4;
    const int q0 = qt * 64 + w * 16;
    const size_t bT = (size_t)b * TT;
    const float c2 = 0.125f * 1.44269504f;        // 1/sqrt(DH) * log2(e)

    bf16x8 qf[2];
    {
        const size_t qoff = (bT + q0 + fr) * 3072 + h * 64 + fg * 8;
        qf[0] = *(const bf16x8*)&qkv[qoff];
        qf[1] = *(const bf16x8*)&qkv[qoff + 32];
    }
    float m[4] = {-1e30f, -1e30f, -1e30f, -1e30f};   // running max, log2 units
    float lse[4] = {0.f, 0.f, 0.f, 0.f};
    f32x4 oacc[4] = {};

    const int srow = t >> 2;            // 0..63: kv row staged by this thread
    const int c8a = (t & 3) * 8;        // elem offset in 64-wide row
    const int ksw = (srow & 7) << 4;
    char* KsB = (char*)Ks;
    char* VtB = (char*)Vt;
    char* PsB = (char*)Ps + w * 2048;   // per-wave 16x64 bf16 P tile

    s16x8 kr0, kr1, vr0, vr1;           // next-tile staging registers (T14)
    auto preload = [&](int kv0) {
        const size_t roff = (bT + kv0 + srow) * 3072 + h * 64;
        kr0 = *(const s16x8*)&qkv[roff + 1024 + c8a];
        kr1 = *(const s16x8*)&qkv[roff + 1024 + c8a + 32];
        vr0 = *(const s16x8*)&qkv[roff + 2048 + c8a];
        vr1 = *(const s16x8*)&qkv[roff + 2048 + c8a + 32];
    };
    preload(0);

    for (int kv0 = 0; kv0 < TT; kv0 += 64) {
        __syncthreads();                 // previous tile's LDS reads done
        // ---- regs -> LDS: K (swizzled row-major), V^T (transposed) ----
#pragma unroll
        for (int half = 0; half < 2; ++half) {
            const s16x8 kr = half ? kr1 : kr0;
            const s16x8 vr = half ? vr1 : vr0;
            const int c8 = c8a + half * 32;
            *(s16x8*)(KsB + srow * 128 + ((c8 * 2) ^ ksw)) = kr;
#pragma unroll
            for (int j = 0; j < 8; j++) {
                const int d = c8 + j;
                const int dsw = (((d & 7) ^ ((d >> 3) & 7)) << 4);
                *(short*)(VtB + d * 128 + ((srow * 2) ^ dsw)) = vr[j];
            }
        }
        __syncthreads();                 // LDS tile ready
        if (kv0 + 64 < TT) preload(kv0 + 64);   // issue next tile's loads early

        // ---- S = Q K^T (per wave: 16 q x 64 kv) ----
        f32x4 sacc[4] = {};
#pragma unroll
        for (int nt = 0; nt < 4; nt++) {
            const int kr_ = nt * 16 + fr;
            const int sw = (kr_ & 7) << 4;
#pragma unroll
            for (int c = 0; c < 2; c++) {
                bf16x8 kf = *(const bf16x8*)(KsB + kr_ * 128 + ((c * 64 + fg * 16) ^ sw));
                sacc[nt] = mfma16x16x32(qf[c], kf, sacc[nt]);
            }
        }
        // ---- online softmax, exp2 domain; q-rows live as fg*4+rg, cols nt*16+fr ----
        float tm2[4];
#pragma unroll
        for (int rg = 0; rg < 4; rg++) {
            float tm = fmaxf(fmaxf(sacc[0][rg], sacc[1][rg]), fmaxf(sacc[2][rg], sacc[3][rg]));
            tm = fmaxf(tm, __shfl_xor(tm, 1));
            tm = fmaxf(tm, __shfl_xor(tm, 2));
            tm = fmaxf(tm, __shfl_xor(tm, 4));
            tm = fmaxf(tm, __shfl_xor(tm, 8));
            tm2[rg] = tm * c2;
        }
        const float need = fmaxf(fmaxf(tm2[0] - m[0], tm2[1] - m[1]),
                                 fmaxf(tm2[2] - m[2], tm2[3] - m[3]));
        if (!__all(need <= 11.5f)) {     // T13 defer-max (~8/ln2 in log2 units)
#pragma unroll
            for (int rg = 0; rg < 4; rg++) {
                const float mn = fmaxf(m[rg], tm2[rg]);
                const float co = exp2f(m[rg] - mn);
                lse[rg] *= co;
                m[rg] = mn;
#pragma unroll
                for (int nd = 0; nd < 4; nd++) oacc[nd][rg] *= co;
            }
        }
        float pv[4][4];
#pragma unroll
        for (int rg = 0; rg < 4; rg++) {
            float rs = 0.f;
#pragma unroll
            for (int nt = 0; nt < 4; nt++) {
                const float p = exp2f(sacc[nt][rg] * c2 - m[rg]);
                pv[nt][rg] = p;
                rs += p;
            }
            rs += __shfl_xor(rs, 1);
            rs += __shfl_xor(rs, 2);
            rs += __shfl_xor(rs, 4);
            rs += __shfl_xor(rs, 8);
            lse[rg] += rs;
        }
        // ---- P -> per-wave LDS (D-layout scatter, swizzled rows) ----
#pragma unroll
        for (int nt = 0; nt < 4; nt++) {
#pragma unroll
            for (int rg = 0; rg < 4; rg++) {
                const int pr_ = fg * 4 + rg;
                *(bf16_t*)(PsB + pr_ * 128 + ((nt * 32 + fr * 2) ^ ((pr_ & 7) << 4))) =
                    (bf16_t)pv[nt][rg];
            }
        }
        // wave-private P: no barrier needed before reading it back
        bf16x8 pf[2];
        {
            const int sw = (fr & 7) << 4;
            pf[0] = *(const bf16x8*)(PsB + fr * 128 + ((fg * 16) ^ sw));
            pf[1] = *(const bf16x8*)(PsB + fr * 128 + ((64 + fg * 16) ^ sw));
        }
        // ---- O += P V ----
#pragma unroll
        for (int nd = 0; nd < 4; nd++) {
            const int dr = nd * 16 + fr;
            const int dsw = (((dr & 7) ^ ((dr >> 3) & 7)) << 4);
#pragma unroll
            for (int c = 0; c < 2; c++) {
                bf16x8 vf = *(const bf16x8*)(VtB + dr * 128 + ((c * 64 + fg * 16) ^ dsw));
                oacc[nd] = mfma16x16x32(pf[c], vf, oacc[nd]);
            }
        }
    }
    // ---- normalize + write y ----
#pragma unroll
    for (int rg = 0; rg < 4; rg++) {
        const float inv = 1.f / lse[rg];
        const size_t ro = (bT + q0 + fg * 4 + rg) * CC + h * 64;
#pragma unroll
        for (int nd = 0; nd < 4; nd++)
            y[ro + nd * 16 + fr] = (bf16_t)(oacc[nd][rg] * inv);
    }
}

// ---------------- host ----------------

extern "C" void kernel_launch(void* const* d_in, const int* in_sizes, int n_in,
                              void* d_out, int out_size, void* d_ws, size_t ws_size,
                              hipStream_t stream) {
    (void)in_sizes; (void)n_in; (void)out_size; (void)ws_size;
    const float* seq  = (const float*)d_in[0];
    const float* pos  = (const float*)d_in[1];
    const float* Wq   = (const float*)d_in[2];
    const float* bq   = (const float*)d_in[3];
    const float* Wk   = (const float*)d_in[4];
    const float* bk   = (const float*)d_in[5];
    const float* Wv   = (const float*)d_in[6];
    const float* bv   = (const float*)d_in[7];
    const float* Wo   = (const float*)d_in[8];
    const float* bo   = (const float*)d_in[9];
    const float* ln1w = (const float*)d_in[10];
    const float* ln1b = (const float*)d_in[11];
    const float* ln2w = (const float*)d_in[12];
    const float* ln2b = (const float*)d_in[13];
    const float* W1   = (const float*)d_in[14];
    const float* b1   = (const float*)d_in[15];
    const float* W2   = (const float*)d_in[16];
    const float* b2   = (const float*)d_in[17];
    const float* lnfw = (const float*)d_in[18];
    const float* lnfb = (const float*)d_in[19];
    const float* Wh   = (const float*)d_in[20];
    float* out = (float*)d_out;

    // workspace layout (bytes) — total ~138 MB
    char* ws = (char*)d_ws;
    float*  x     = (float*)(ws + 0);            // 32 MB fp32 residual stream
    bf16_t* qkvb  = (bf16_t*)(ws + 33554432);    // 48 MB
    bf16_t* yb    = (bf16_t*)(ws + 83886080);    // 16 MB
    bf16_t* a1b   = (bf16_t*)(ws + 33554432);    // 64 MB, aliases qkv+y (dead by MLP1)
    bf16_t* hb    = (bf16_t*)(ws + 100663296);   // 16 MB (LN output)
    bf16_t* wqkvb = (bf16_t*)(ws + 117440512);   // 6 MB
    bf16_t* wob   = (bf16_t*)(ws + 123731968);   // 2 MB
    bf16_t* w1b   = (bf16_t*)(ws + 125829120);   // 8 MB
    bf16_t* w2b   = (bf16_t*)(ws + 134217728);   // 8 MB
    bf16_t* whb   = (bf16_t*)(ws + 142606336);   // 2 MB
    float*  bqkv  = (float*)(ws + 144703488);    // 12 KB

    f32_to_bf16_k<<<1024, 256, 0, stream>>>(Wh, whb, 262144);
    add_pos_k<<<8192, 256, 0, stream>>>(seq, pos, x);

    for (int l = 0; l < LAYERS; ++l) {
        const size_t wo_ = (size_t)l * CC * CC;
        const size_t w4_ = (size_t)l * 4 * CC * CC;
        convert_layer_k<<<12291, 256, 0, stream>>>(Wq + wo_, Wk + wo_, Wv + wo_, Wo + wo_,
                                                   W1 + w4_, W2 + w4_,
                                                   bq + l * CC, bk + l * CC, bv + l * CC,
                                                   wqkvb, wob, w1b, w2b, bqkv);

        ln_rows_k<<<2048, 256, 0, stream>>>(x, ln1w + l * CC, ln1b + l * CC, hb);
        gemm_bt<EPI_BF16><<<1536, 256, 0, stream>>>(hb, wqkvb, bqkv, nullptr,
                                                    qkvb, nullptr, 3072, 1024, 24);
        attn_k<<<2048, 256, 0, stream>>>(qkvb, yb);
        gemm_bt<EPI_RES><<<512, 256, 0, stream>>>(yb, wob, bo + l * CC, x,
                                                  nullptr, nullptr, 1024, 1024, 8);
        ln_rows_k<<<2048, 256, 0, stream>>>(x, ln2w + l * CC, ln2b + l * CC, hb);
        gemm_bt<EPI_GELU><<<2048, 256, 0, stream>>>(hb, w1b, b1 + (size_t)l * 4 * CC,
                                                    nullptr, a1b, nullptr, 4096, 1024, 32);
        gemm_bt<EPI_RES><<<512, 256, 0, stream>>>(a1b, w2b, b2 + l * CC, x,
                                                  nullptr, nullptr, 1024, 4096, 8);
    }
    ln_rows_k<<<2048, 256, 0, stream>>>(x, lnfw, lnfb, hb);
    gemm_bt<EPI_F32><<<512, 256, 0, stream>>>(hb, whb, nullptr, nullptr,
                                              nullptr, out, 1024, 1024, 8);
}

// Round 6
// 4620.187 us; speedup vs baseline: 1.0880x; 1.0880x over previous
//
#include <hip/hip_runtime.h>
#include <hip/hip_bf16.h>

// GPT forward, MI355X. B=4 T=2048 C=1024 H=16 DH=64 L=8 OUT=1024.
// bf16 MFMA (16x16x32) for all GEMMs + flash attention; fp32 residual stream.

#define LAYERS 8
#define NH 16
#define TT 2048
#define CC 1024
#define NB 4
#define MR (NB*TT)          // 8192 token rows
#define LN_EPS 1e-5f

typedef __bf16 bf16_t;
typedef __attribute__((ext_vector_type(8))) __bf16 bf16x8;
typedef __attribute__((ext_vector_type(4))) __bf16 bf16x4;
typedef __attribute__((ext_vector_type(4))) float f32x4;
typedef __attribute__((ext_vector_type(8))) short s16x8;
typedef __attribute__((ext_vector_type(4))) unsigned u32x4;

__device__ inline f32x4 mfma16x16x32(bf16x8 a, bf16x8 b, f32x4 c) {
    return __builtin_amdgcn_mfma_f32_16x16x32_bf16(a, b, c, 0, 0, 0);
}

__device__ inline void gload_lds16(const void* g, void* lds) {
    __builtin_amdgcn_global_load_lds((const __attribute__((address_space(1))) void*)g,
                                     (__attribute__((address_space(3))) void*)lds, 16, 0, 0);
}

__device__ inline unsigned pack_bf16(float a, float b) {
    unsigned short ua = __builtin_bit_cast(unsigned short, (bf16_t)a);
    unsigned short ub = __builtin_bit_cast(unsigned short, (bf16_t)b);
    return (unsigned)ua | ((unsigned)ub << 16);
}

// ---------------- elementwise helpers ----------------

__global__ __launch_bounds__(256) void add_pos_k(const float* __restrict__ s,
                                                 const float* __restrict__ p,
                                                 float* __restrict__ x) {
    int i = blockIdx.x * 256 + threadIdx.x;          // float4 units
    float4 a = ((const float4*)s)[i];
    float4 b = ((const float4*)p)[i & ((TT * CC / 4) - 1)];
    ((float4*)x)[i] = make_float4(a.x + b.x, a.y + b.y, a.z + b.z, a.w + b.w);
}

__global__ __launch_bounds__(256) void f32_to_bf16_k(const float* __restrict__ s,
                                                     bf16_t* __restrict__ d, int n4) {
    int i = blockIdx.x * 256 + threadIdx.x;
    if (i < n4) {
        float4 v = ((const float4*)s)[i];
        bf16x4 o;
        o[0] = (bf16_t)v.x; o[1] = (bf16_t)v.y; o[2] = (bf16_t)v.z; o[3] = (bf16_t)v.w;
        ((bf16x4*)d)[i] = o;
    }
}

// One launch per layer: convert Wq|Wk|Wv -> wqkvb, Wo -> wob, W1 -> w1b,
// W2 -> w2b (f32->bf16, float4-vectorized) and concat bq|bk|bv -> bqkv.
__global__ __launch_bounds__(256) void convert_layer_k(
        const float* __restrict__ Wq, const float* __restrict__ Wk,
        const float* __restrict__ Wv, const float* __restrict__ Wo,
        const float* __restrict__ W1, const float* __restrict__ W2,
        const float* __restrict__ bq, const float* __restrict__ bk,
        const float* __restrict__ bv,
        bf16_t* __restrict__ wqkvb, bf16_t* __restrict__ wob,
        bf16_t* __restrict__ w1b, bf16_t* __restrict__ w2b,
        float* __restrict__ bqkv) {
    const int i = blockIdx.x * 256 + threadIdx.x;    // float4 units
    if (i < 3145728) {
        const float4* s4;
        bf16_t* dst;
        int off;
        if (i < 262144)       { s4 = (const float4*)Wq + i;             dst = wqkvb; off = i; }
        else if (i < 524288)  { s4 = (const float4*)Wk + (i - 262144);  dst = wqkvb; off = i; }
        else if (i < 786432)  { s4 = (const float4*)Wv + (i - 524288);  dst = wqkvb; off = i; }
        else if (i < 1048576) { s4 = (const float4*)Wo + (i - 786432);  dst = wob;   off = i - 786432; }
        else if (i < 2097152) { s4 = (const float4*)W1 + (i - 1048576); dst = w1b;   off = i - 1048576; }
        else                  { s4 = (const float4*)W2 + (i - 2097152); dst = w2b;   off = i - 2097152; }
        float4 v = *s4;
        bf16x4 o;
        o[0] = (bf16_t)v.x; o[1] = (bf16_t)v.y; o[2] = (bf16_t)v.z; o[3] = (bf16_t)v.w;
        ((bf16x4*)dst)[off] = o;
    } else if (i < 3146496) {        // bias concat: 768 f4 = 3072 floats
        const int j = i - 3145728;
        const float* b = (j < 256) ? bq : (j < 512 ? bk : bv);
        ((float4*)bqkv)[j] = ((const float4*)b)[j & 255];
    }
}

// ---------------- LayerNorm: one wave per row, bf16 out ----------------

__global__ __launch_bounds__(256) void ln_rows_k(const float* __restrict__ x,
                                                 const float* __restrict__ wgt,
                                                 const float* __restrict__ bgt,
                                                 bf16_t* __restrict__ out) {
    const int row = blockIdx.x * 4 + (threadIdx.x >> 6);
    const int l = threadIdx.x & 63;
    const float* xr = x + (size_t)row * CC;
    float4 v[4];
    float s = 0.f, sq = 0.f;
#pragma unroll
    for (int j = 0; j < 4; j++) {
        v[j] = *(const float4*)&xr[j * 256 + l * 4];
        s  += v[j].x + v[j].y + v[j].z + v[j].w;
        sq += v[j].x * v[j].x + v[j].y * v[j].y + v[j].z * v[j].z + v[j].w * v[j].w;
    }
#pragma unroll
    for (int m = 1; m < 64; m <<= 1) { s += __shfl_xor(s, m); sq += __shfl_xor(sq, m); }
    const float mu = s * (1.f / CC);
    const float rstd = rsqrtf(sq * (1.f / CC) - mu * mu + LN_EPS);
#pragma unroll
    for (int j = 0; j < 4; j++) {
        const int c0 = j * 256 + l * 4;
        const float4 wv = *(const float4*)&wgt[c0];
        const float4 bv = *(const float4*)&bgt[c0];
        bf16x4 o;
        o[0] = (bf16_t)((v[j].x - mu) * rstd * wv.x + bv.x);
        o[1] = (bf16_t)((v[j].y - mu) * rstd * wv.y + bv.y);
        o[2] = (bf16_t)((v[j].z - mu) * rstd * wv.z + bv.z);
        o[3] = (bf16_t)((v[j].w - mu) * rstd * wv.w + bv.w);
        *(bf16x4*)&out[(size_t)row * CC + c0] = o;
    }
}

// ---------------- GEMM: C[M,N] = A[M,K] @ B[N,K]^T, m97 structure ----------------
// 128x128 tile, BK=32, 4 waves each 64x64 (4x4 of 16x16x32 MFMA), global_load_lds.
// 1D grid with XCD-aware swizzle (T1); all grids are %8==0 so the simple
// bijective form is valid.

#define EPI_BF16 0   // obf = acc + bias
#define EPI_GELU 1   // obf = gelu(acc + bias)
#define EPI_RES  2   // resid(fp32,[M][CC]) += acc + bias
#define EPI_F32  3   // of32 = acc (no bias)

template <int EPI>
__global__ __launch_bounds__(256) void gemm_bt(const bf16_t* __restrict__ A,
                                               const bf16_t* __restrict__ Bw,
                                               const float* __restrict__ bias,
                                               float* __restrict__ resid,
                                               bf16_t* __restrict__ obf,
                                               float* __restrict__ of32,
                                               int N, int K, int nbn) {
    __shared__ __align__(16) bf16_t As[128 * 32];
    __shared__ __align__(16) bf16_t Bs[128 * 32];
    const int nwg = gridDim.x;
    const int id = blockIdx.x;
    const int swz = (id & 7) * (nwg >> 3) + (id >> 3);
    const int bn = swz % nbn, bm = swz / nbn;
    const int t = threadIdx.x, w = t >> 6, l = t & 63;
    const int wm = (w >> 1) << 6, wn = (w & 1) << 6;
    const int fr = l & 15, fg = l >> 4;
    const int srow = l >> 2, scol = (l & 3) * 8;   // lane -> (row, 8-elem chunk), LDS-linear
    f32x4 acc[4][4] = {};
    for (int k0 = 0; k0 < K; k0 += 32) {
#pragma unroll
        for (int it = 0; it < 2; ++it) {
            const int rr = it * 64 + w * 16;
            gload_lds16(A  + (size_t)(bm * 128 + rr + srow) * K + k0 + scol, &As[rr * 32]);
            gload_lds16(Bw + (size_t)(bn * 128 + rr + srow) * K + k0 + scol, &Bs[rr * 32]);
        }
        __syncthreads();
        bf16x8 af[4], bfv[4];
#pragma unroll
        for (int i = 0; i < 4; i++) af[i]  = *(const bf16x8*)&As[(wm + i * 16 + fr) * 32 + fg * 8];
#pragma unroll
        for (int j = 0; j < 4; j++) bfv[j] = *(const bf16x8*)&Bs[(wn + j * 16 + fr) * 32 + fg * 8];
#pragma unroll
        for (int i = 0; i < 4; i++)
#pragma unroll
            for (int j = 0; j < 4; j++)
                acc[i][j] = mfma16x16x32(af[i], bfv[j], acc[i][j]);
        __syncthreads();
    }
    // C/D layout: col = lane&15, row = (lane>>4)*4 + reg  [m89-verified]
#pragma unroll
    for (int i = 0; i < 4; i++) {
#pragma unroll
        for (int j = 0; j < 4; j++) {
            const int col = bn * 128 + wn + j * 16 + fr;
            float bv = 0.f;
            if constexpr (EPI != EPI_F32) bv = bias[col];
#pragma unroll
            for (int rg = 0; rg < 4; ++rg) {
                const int row = bm * 128 + wm + i * 16 + fg * 4 + rg;
                float v = acc[i][j][rg] + bv;
                if constexpr (EPI == EPI_BF16) {
                    obf[(size_t)row * N + col] = (bf16_t)v;
                } else if constexpr (EPI == EPI_GELU) {
                    v = 0.5f * v * (1.0f + erff(v * 0.70710678118f));
                    obf[(size_t)row * N + col] = (bf16_t)v;
                } else if constexpr (EPI == EPI_RES) {
                    resid[(size_t)row * CC + col] += v;
                } else {
                    of32[(size_t)row * N + col] = v;
                }
            }
        }
    }
}

// ---------------- Flash attention (v2: swapped QK^T, in-register P) ----------------
// qkv: [MR][3C] bf16 (q|k|v). Per block: one (b,h), 64 q-rows; 4 waves x 16 q-rows.
// KV tiles of 64. S^T = mfma(K, Q): lane fr = one q-column -> softmax needs only
// 2 shfls (xor 16/32), scalar m/lse. P redistributed to PV A-fragments entirely
// in-register (12 packed shfl_xor + selects) -- no P LDS round-trip. K staged
// swizzled row-major; V^T staged transposed (two-term XOR swizzle). Defer-max
// (T13), exp2 domain, next-tile preload (T14-lite). LDS 16KB.

__global__ __launch_bounds__(256, 4) void attn_k(const bf16_t* __restrict__ qkv,
                                                 bf16_t* __restrict__ y) {
    __shared__ __align__(16) bf16_t Ks[64 * 64];
    __shared__ __align__(16) bf16_t Vt[64 * 64];
    const int id = blockIdx.x;                    // 2048 blocks, %8==0
    const int swz = (id & 7) * 256 + (id >> 3);   // XCD swizzle: same bh -> same XCD
    const int qt = swz & 31, bh = swz >> 5;
    const int b = bh >> 4, h = bh & 15;
    const int t = threadIdx.x, w = t >> 6, l = t & 63;
    const int fr = l & 15, fg = l >> 4;
    const int hh = fg >> 1;                       // P-pack selector (0/1)
    const int q0 = qt * 64 + w * 16;
    const size_t bT = (size_t)b * TT;
    const float SCL = 0.125f * 1.44269504f;       // 1/sqrt(DH) * log2(e)

    bf16x8 qf[2];
    {
        const size_t qoff = (bT + q0 + fr) * 3072 + h * 64 + fg * 8;
        qf[0] = *(const bf16x8*)&qkv[qoff];
        qf[1] = *(const bf16x8*)&qkv[qoff + 32];
    }
    float mrun = -1e30f, lse = 0.f;               // per-lane, for q = fr (log2 units)
    f32x4 oacc[4] = {};                           // O[q=fg*4+rg][d=nd*16+fr]

    const int srow = t >> 2;            // 0..63: kv row staged by this thread
    const int c8a = (t & 3) * 8;        // elem offset in 64-wide row
    const int ksw = (srow & 7) << 4;
    char* KsB = (char*)Ks;
    char* VtB = (char*)Vt;

    s16x8 kr0, kr1, vr0, vr1;           // next-tile staging registers (T14)
    auto preload = [&](int kv0) {
        const size_t roff = (bT + kv0 + srow) * 3072 + h * 64;
        kr0 = *(const s16x8*)&qkv[roff + 1024 + c8a];
        kr1 = *(const s16x8*)&qkv[roff + 1024 + c8a + 32];
        vr0 = *(const s16x8*)&qkv[roff + 2048 + c8a];
        vr1 = *(const s16x8*)&qkv[roff + 2048 + c8a + 32];
    };
    preload(0);

    for (int kv0 = 0; kv0 < TT; kv0 += 64) {
        __syncthreads();                 // previous tile's LDS reads done
        // ---- regs -> LDS: K (swizzled row-major), V^T (transposed) ----
#pragma unroll
        for (int half = 0; half < 2; ++half) {
            const s16x8 kr = half ? kr1 : kr0;
            const s16x8 vr = half ? vr1 : vr0;
            const int c8 = c8a + half * 32;
            *(s16x8*)(KsB + srow * 128 + ((c8 * 2) ^ ksw)) = kr;
#pragma unroll
            for (int j = 0; j < 8; j++) {
                const int d = c8 + j;
                const int dsw = (((d & 7) ^ ((d >> 3) & 7)) << 4);
                *(short*)(VtB + d * 128 + ((srow * 2) ^ dsw)) = vr[j];
            }
        }
        __syncthreads();                 // LDS tile ready
        if (kv0 + 64 < TT) preload(kv0 + 64);   // issue next tile's loads early

        // ---- S^T = K Q^T: sacc[nt] rows k=16nt+fg*4+rg, col q=fr ----
        f32x4 sacc[4] = {};
#pragma unroll
        for (int nt = 0; nt < 4; nt++) {
            const int kr_ = nt * 16 + fr;
            const int sw = (kr_ & 7) << 4;
#pragma unroll
            for (int c = 0; c < 2; c++) {
                bf16x8 kf = *(const bf16x8*)(KsB + kr_ * 128 + ((c * 64 + fg * 16) ^ sw));
                sacc[nt] = mfma16x16x32(kf, qf[c], sacc[nt]);
            }
        }
        // ---- per-lane softmax over k (16 in-reg + cross-fg xor16/32) ----
        float tm = sacc[0][0];
#pragma unroll
        for (int nt = 0; nt < 4; nt++)
#pragma unroll
            for (int rg = 0; rg < 4; rg++) tm = fmaxf(tm, sacc[nt][rg]);
        tm = fmaxf(tm, __shfl_xor(tm, 16));
        tm = fmaxf(tm, __shfl_xor(tm, 32));
        tm *= SCL;
        if (!__all(tm - mrun <= 11.5f)) {        // T13 defer-max (~8/ln2)
            const float mn = fmaxf(mrun, tm);
            const float co = exp2f(mrun - mn);
            lse *= co; mrun = mn;
            const float cr0 = __shfl(co, fg * 4 + 0);
            const float cr1 = __shfl(co, fg * 4 + 1);
            const float cr2 = __shfl(co, fg * 4 + 2);
            const float cr3 = __shfl(co, fg * 4 + 3);
#pragma unroll
            for (int nd = 0; nd < 4; nd++) {
                oacc[nd][0] *= cr0; oacc[nd][1] *= cr1;
                oacc[nd][2] *= cr2; oacc[nd][3] *= cr3;
            }
        }
        // ---- P = exp2(S^T*SCL - m), packed (c0,c1) for redistribution ----
        // static-index copies of sacc by hh (rule #20: no runtime reg indexing)
        const f32x4 sA0 = hh ? sacc[1] : sacc[0];     // nt = hh
        const f32x4 sA1 = hh ? sacc[3] : sacc[2];     // nt = 2+hh
        const f32x4 sB0 = hh ? sacc[0] : sacc[1];     // nt = hh^1
        const f32x4 sB1 = hh ? sacc[2] : sacc[3];     // nt = 2+(hh^1)
        float rs = 0.f;
        unsigned pkA[4], pkB[4];
#pragma unroll
        for (int rg = 0; rg < 4; rg++) {
            const float a0 = exp2f(sA0[rg] * SCL - mrun);
            const float a1 = exp2f(sA1[rg] * SCL - mrun);
            const float b0 = exp2f(sB0[rg] * SCL - mrun);
            const float b1 = exp2f(sB1[rg] * SCL - mrun);
            rs += (a0 + a1) + (b0 + b1);
            pkA[rg] = pack_bf16(a0, a1);
            pkB[rg] = pack_bf16(b0, b1);
        }
        rs += __shfl_xor(rs, 16);
        rs += __shfl_xor(rs, 32);
        lse += rs;
        // ---- redistribute P^T -> PV A-fragments (derivation in notes):
        // paf[c][4s+rg] = P[q=fr][k=32c+8fg+4s+rg], source lane fg' = 2(fg&1)+s,
        // nt = 2c+(fg>>1). Contributor for mask x sends pv[2c+((fg^x)>>1)][rg]:
        // x16 -> pkA, x32/x48 -> pkB.
        unsigned s0pk[4], s1pk[4];
#pragma unroll
        for (int rg = 0; rg < 4; rg++) {
            const unsigned r16 = __shfl_xor(pkA[rg], 16);
            const unsigned r32 = __shfl_xor(pkB[rg], 32);
            const unsigned r48 = __shfl_xor(pkB[rg], 48);
            s0pk[rg] = (fg == 0) ? pkA[rg] : (fg == 1) ? r48 : (fg == 2) ? r32 : r16;
            s1pk[rg] = (fg == 0) ? r16 : (fg == 1) ? r32 : (fg == 2) ? r48 : pkA[rg];
        }
        u32x4 w0v, w1v;
        w0v[0] = (s0pk[0] & 0xFFFFu) | (s0pk[1] << 16);
        w0v[1] = (s0pk[2] & 0xFFFFu) | (s0pk[3] << 16);
        w0v[2] = (s1pk[0] & 0xFFFFu) | (s1pk[1] << 16);
        w0v[3] = (s1pk[2] & 0xFFFFu) | (s1pk[3] << 16);
        w1v[0] = (s0pk[0] >> 16) | (s0pk[1] & 0xFFFF0000u);
        w1v[1] = (s0pk[2] >> 16) | (s0pk[3] & 0xFFFF0000u);
        w1v[2] = (s1pk[0] >> 16) | (s1pk[1] & 0xFFFF0000u);
        w1v[3] = (s1pk[2] >> 16) | (s1pk[3] & 0xFFFF0000u);
        const bf16x8 paf0 = __builtin_bit_cast(bf16x8, w0v);
        const bf16x8 paf1 = __builtin_bit_cast(bf16x8, w1v);
        // ---- O += P V ----
#pragma unroll
        for (int nd = 0; nd < 4; nd++) {
            const int dr = nd * 16 + fr;
            const int dsw = (((dr & 7) ^ ((dr >> 3) & 7)) << 4);
            bf16x8 vf0 = *(const bf16x8*)(VtB + dr * 128 + ((fg * 16) ^ dsw));
            oacc[nd] = mfma16x16x32(paf0, vf0, oacc[nd]);
            bf16x8 vf1 = *(const bf16x8*)(VtB + dr * 128 + ((64 + fg * 16) ^ dsw));
            oacc[nd] = mfma16x16x32(paf1, vf1, oacc[nd]);
        }
    }
    // ---- normalize + write y (O rows q=fg*4+rg need per-row 1/lse via shfl) ----
    const float inv = 1.f / lse;
    const float i0 = __shfl(inv, fg * 4 + 0);
    const float i1 = __shfl(inv, fg * 4 + 1);
    const float i2 = __shfl(inv, fg * 4 + 2);
    const float i3 = __shfl(inv, fg * 4 + 3);
#pragma unroll
    for (int nd = 0; nd < 4; nd++) {
        const size_t ro = (bT + q0 + fg * 4) * CC + h * 64 + nd * 16 + fr;
        y[ro]          = (bf16_t)(oacc[nd][0] * i0);
        y[ro + CC]     = (bf16_t)(oacc[nd][1] * i1);
        y[ro + 2 * CC] = (bf16_t)(oacc[nd][2] * i2);
        y[ro + 3 * CC] = (bf16_t)(oacc[nd][3] * i3);
    }
}

// ---------------- host ----------------

extern "C" void kernel_launch(void* const* d_in, const int* in_sizes, int n_in,
                              void* d_out, int out_size, void* d_ws, size_t ws_size,
                              hipStream_t stream) {
    (void)in_sizes; (void)n_in; (void)out_size; (void)ws_size;
    const float* seq  = (const float*)d_in[0];
    const float* pos  = (const float*)d_in[1];
    const float* Wq   = (const float*)d_in[2];
    const float* bq   = (const float*)d_in[3];
    const float* Wk   = (const float*)d_in[4];
    const float* bk   = (const float*)d_in[5];
    const float* Wv   = (const float*)d_in[6];
    const float* bv   = (const float*)d_in[7];
    const float* Wo   = (const float*)d_in[8];
    const float* bo   = (const float*)d_in[9];
    const float* ln1w = (const float*)d_in[10];
    const float* ln1b = (const float*)d_in[11];
    const float* ln2w = (const float*)d_in[12];
    const float* ln2b = (const float*)d_in[13];
    const float* W1   = (const float*)d_in[14];
    const float* b1   = (const float*)d_in[15];
    const float* W2   = (const float*)d_in[16];
    const float* b2   = (const float*)d_in[17];
    const float* lnfw = (const float*)d_in[18];
    const float* lnfb = (const float*)d_in[19];
    const float* Wh   = (const float*)d_in[20];
    float* out = (float*)d_out;

    // workspace layout (bytes) — total ~138 MB
    char* ws = (char*)d_ws;
    float*  x     = (float*)(ws + 0);            // 32 MB fp32 residual stream
    bf16_t* qkvb  = (bf16_t*)(ws + 33554432);    // 48 MB
    bf16_t* yb    = (bf16_t*)(ws + 83886080);    // 16 MB
    bf16_t* a1b   = (bf16_t*)(ws + 33554432);    // 64 MB, aliases qkv+y (dead by MLP1)
    bf16_t* hb    = (bf16_t*)(ws + 100663296);   // 16 MB (LN output)
    bf16_t* wqkvb = (bf16_t*)(ws + 117440512);   // 6 MB
    bf16_t* wob   = (bf16_t*)(ws + 123731968);   // 2 MB
    bf16_t* w1b   = (bf16_t*)(ws + 125829120);   // 8 MB
    bf16_t* w2b   = (bf16_t*)(ws + 134217728);   // 8 MB
    bf16_t* whb   = (bf16_t*)(ws + 142606336);   // 2 MB
    float*  bqkv  = (float*)(ws + 144703488);    // 12 KB

    f32_to_bf16_k<<<1024, 256, 0, stream>>>(Wh, whb, 262144);
    add_pos_k<<<8192, 256, 0, stream>>>(seq, pos, x);

    for (int l = 0; l < LAYERS; ++l) {
        const size_t wo_ = (size_t)l * CC * CC;
        const size_t w4_ = (size_t)l * 4 * CC * CC;
        convert_layer_k<<<12291, 256, 0, stream>>>(Wq + wo_, Wk + wo_, Wv + wo_, Wo + wo_,
                                                   W1 + w4_, W2 + w4_,
                                                   bq + l * CC, bk + l * CC, bv + l * CC,
                                                   wqkvb, wob, w1b, w2b, bqkv);

        ln_rows_k<<<2048, 256, 0, stream>>>(x, ln1w + l * CC, ln1b + l * CC, hb);
        gemm_bt<EPI_BF16><<<1536, 256, 0, stream>>>(hb, wqkvb, bqkv, nullptr,
                                                    qkvb, nullptr, 3072, 1024, 24);
        attn_k<<<2048, 256, 0, stream>>>(qkvb, yb);
        gemm_bt<EPI_RES><<<512, 256, 0, stream>>>(yb, wob, bo + l * CC, x,
                                                  nullptr, nullptr, 1024, 1024, 8);
        ln_rows_k<<<2048, 256, 0, stream>>>(x, ln2w + l * CC, ln2b + l * CC, hb);
        gemm_bt<EPI_GELU><<<2048, 256, 0, stream>>>(hb, w1b, b1 + (size_t)l * 4 * CC,
                                                    nullptr, a1b, nullptr, 4096, 1024, 32);
        gemm_bt<EPI_RES><<<512, 256, 0, stream>>>(a1b, w2b, b2 + l * CC, x,
                                                  nullptr, nullptr, 1024, 4096, 8);
    }
    ln_rows_k<<<2048, 256, 0, stream>>>(x, lnfw, lnfb, hb);
    gemm_bt<EPI_F32><<<512, 256, 0, stream>>>(hb, whb, nullptr, nullptr,
                                              nullptr, out, 1024, 1024, 8);
}

// Round 7
// 4309.772 us; speedup vs baseline: 1.1663x; 1.0720x over previous
//
#include <hip/hip_runtime.h>
#include <hip/hip_bf16.h>

// GPT forward, MI355X. B=4 T=2048 C=1024 H=16 DH=64 L=8 OUT=1024.
// bf16 MFMA (16x16x32) for all GEMMs + flash attention; fp32 residual stream.

#define LAYERS 8
#define NH 16
#define TT 2048
#define CC 1024
#define NB 4
#define MR (NB*TT)          // 8192 token rows
#define LN_EPS 1e-5f

typedef __bf16 bf16_t;
typedef __attribute__((ext_vector_type(8))) __bf16 bf16x8;
typedef __attribute__((ext_vector_type(4))) __bf16 bf16x4;
typedef __attribute__((ext_vector_type(4))) float f32x4;
typedef __attribute__((ext_vector_type(8))) short s16x8;
typedef __attribute__((ext_vector_type(4))) unsigned u32x4;

__device__ inline f32x4 mfma16x16x32(bf16x8 a, bf16x8 b, f32x4 c) {
    return __builtin_amdgcn_mfma_f32_16x16x32_bf16(a, b, c, 0, 0, 0);
}

__device__ inline void gload_lds16(const void* g, void* lds) {
    __builtin_amdgcn_global_load_lds((const __attribute__((address_space(1))) void*)g,
                                     (__attribute__((address_space(3))) void*)lds, 16, 0, 0);
}

__device__ inline unsigned pack_bf16(float a, float b) {
    unsigned short ua = __builtin_bit_cast(unsigned short, (bf16_t)a);
    unsigned short ub = __builtin_bit_cast(unsigned short, (bf16_t)b);
    return (unsigned)ua | ((unsigned)ub << 16);
}

// ---------------- elementwise helpers ----------------

__global__ __launch_bounds__(256) void add_pos_k(const float* __restrict__ s,
                                                 const float* __restrict__ p,
                                                 float* __restrict__ x) {
    int i = blockIdx.x * 256 + threadIdx.x;          // float4 units
    float4 a = ((const float4*)s)[i];
    float4 b = ((const float4*)p)[i & ((TT * CC / 4) - 1)];
    ((float4*)x)[i] = make_float4(a.x + b.x, a.y + b.y, a.z + b.z, a.w + b.w);
}

__global__ __launch_bounds__(256) void f32_to_bf16_k(const float* __restrict__ s,
                                                     bf16_t* __restrict__ d, int n4) {
    int i = blockIdx.x * 256 + threadIdx.x;
    if (i < n4) {
        float4 v = ((const float4*)s)[i];
        bf16x4 o;
        o[0] = (bf16_t)v.x; o[1] = (bf16_t)v.y; o[2] = (bf16_t)v.z; o[3] = (bf16_t)v.w;
        ((bf16x4*)d)[i] = o;
    }
}

// One launch per layer: convert Wq|Wk|Wv -> wqkvb, Wo -> wob, W1 -> w1b,
// W2 -> w2b (f32->bf16, float4-vectorized) and concat bq|bk|bv -> bqkv.
__global__ __launch_bounds__(256) void convert_layer_k(
        const float* __restrict__ Wq, const float* __restrict__ Wk,
        const float* __restrict__ Wv, const float* __restrict__ Wo,
        const float* __restrict__ W1, const float* __restrict__ W2,
        const float* __restrict__ bq, const float* __restrict__ bk,
        const float* __restrict__ bv,
        bf16_t* __restrict__ wqkvb, bf16_t* __restrict__ wob,
        bf16_t* __restrict__ w1b, bf16_t* __restrict__ w2b,
        float* __restrict__ bqkv) {
    const int i = blockIdx.x * 256 + threadIdx.x;    // float4 units
    if (i < 3145728) {
        const float4* s4;
        bf16_t* dst;
        int off;
        if (i < 262144)       { s4 = (const float4*)Wq + i;             dst = wqkvb; off = i; }
        else if (i < 524288)  { s4 = (const float4*)Wk + (i - 262144);  dst = wqkvb; off = i; }
        else if (i < 786432)  { s4 = (const float4*)Wv + (i - 524288);  dst = wqkvb; off = i; }
        else if (i < 1048576) { s4 = (const float4*)Wo + (i - 786432);  dst = wob;   off = i - 786432; }
        else if (i < 2097152) { s4 = (const float4*)W1 + (i - 1048576); dst = w1b;   off = i - 1048576; }
        else                  { s4 = (const float4*)W2 + (i - 2097152); dst = w2b;   off = i - 2097152; }
        float4 v = *s4;
        bf16x4 o;
        o[0] = (bf16_t)v.x; o[1] = (bf16_t)v.y; o[2] = (bf16_t)v.z; o[3] = (bf16_t)v.w;
        ((bf16x4*)dst)[off] = o;
    } else if (i < 3146496) {        // bias concat: 768 f4 = 3072 floats
        const int j = i - 3145728;
        const float* b = (j < 256) ? bq : (j < 512 ? bk : bv);
        ((float4*)bqkv)[j] = ((const float4*)b)[j & 255];
    }
}

// ---------------- LayerNorm: one wave per row, bf16 out ----------------

__global__ __launch_bounds__(256) void ln_rows_k(const float* __restrict__ x,
                                                 const float* __restrict__ wgt,
                                                 const float* __restrict__ bgt,
                                                 bf16_t* __restrict__ out) {
    const int row = blockIdx.x * 4 + (threadIdx.x >> 6);
    const int l = threadIdx.x & 63;
    const float* xr = x + (size_t)row * CC;
    float4 v[4];
    float s = 0.f, sq = 0.f;
#pragma unroll
    for (int j = 0; j < 4; j++) {
        v[j] = *(const float4*)&xr[j * 256 + l * 4];
        s  += v[j].x + v[j].y + v[j].z + v[j].w;
        sq += v[j].x * v[j].x + v[j].y * v[j].y + v[j].z * v[j].z + v[j].w * v[j].w;
    }
#pragma unroll
    for (int m = 1; m < 64; m <<= 1) { s += __shfl_xor(s, m); sq += __shfl_xor(sq, m); }
    const float mu = s * (1.f / CC);
    const float rstd = rsqrtf(sq * (1.f / CC) - mu * mu + LN_EPS);
#pragma unroll
    for (int j = 0; j < 4; j++) {
        const int c0 = j * 256 + l * 4;
        const float4 wv = *(const float4*)&wgt[c0];
        const float4 bv = *(const float4*)&bgt[c0];
        bf16x4 o;
        o[0] = (bf16_t)((v[j].x - mu) * rstd * wv.x + bv.x);
        o[1] = (bf16_t)((v[j].y - mu) * rstd * wv.y + bv.y);
        o[2] = (bf16_t)((v[j].z - mu) * rstd * wv.z + bv.z);
        o[3] = (bf16_t)((v[j].w - mu) * rstd * wv.w + bv.w);
        *(bf16x4*)&out[(size_t)row * CC + c0] = o;
    }
}

// ---------------- GEMM (small-N): m97 structure, 128x128 tile, BK=32 ----------------

#define EPI_BF16 0   // obf = acc + bias
#define EPI_GELU 1   // obf = gelu(acc + bias)
#define EPI_RES  2   // resid(fp32,[M][CC]) += acc + bias
#define EPI_F32  3   // of32 = acc (no bias)

template <int EPI>
__global__ __launch_bounds__(256) void gemm_bt(const bf16_t* __restrict__ A,
                                               const bf16_t* __restrict__ Bw,
                                               const float* __restrict__ bias,
                                               float* __restrict__ resid,
                                               bf16_t* __restrict__ obf,
                                               float* __restrict__ of32,
                                               int N, int K, int nbn) {
    __shared__ __align__(16) bf16_t As[128 * 32];
    __shared__ __align__(16) bf16_t Bs[128 * 32];
    const int nwg = gridDim.x;
    const int id = blockIdx.x;
    const int swz = (id & 7) * (nwg >> 3) + (id >> 3);
    const int bn = swz % nbn, bm = swz / nbn;
    const int t = threadIdx.x, w = t >> 6, l = t & 63;
    const int wm = (w >> 1) << 6, wn = (w & 1) << 6;
    const int fr = l & 15, fg = l >> 4;
    const int srow = l >> 2, scol = (l & 3) * 8;   // lane -> (row, 8-elem chunk), LDS-linear
    f32x4 acc[4][4] = {};
    for (int k0 = 0; k0 < K; k0 += 32) {
#pragma unroll
        for (int it = 0; it < 2; ++it) {
            const int rr = it * 64 + w * 16;
            gload_lds16(A  + (size_t)(bm * 128 + rr + srow) * K + k0 + scol, &As[rr * 32]);
            gload_lds16(Bw + (size_t)(bn * 128 + rr + srow) * K + k0 + scol, &Bs[rr * 32]);
        }
        __syncthreads();
        bf16x8 af[4], bfv[4];
#pragma unroll
        for (int i = 0; i < 4; i++) af[i]  = *(const bf16x8*)&As[(wm + i * 16 + fr) * 32 + fg * 8];
#pragma unroll
        for (int j = 0; j < 4; j++) bfv[j] = *(const bf16x8*)&Bs[(wn + j * 16 + fr) * 32 + fg * 8];
#pragma unroll
        for (int i = 0; i < 4; i++)
#pragma unroll
            for (int j = 0; j < 4; j++)
                acc[i][j] = mfma16x16x32(af[i], bfv[j], acc[i][j]);
        __syncthreads();
    }
    // C/D layout: col = lane&15, row = (lane>>4)*4 + reg  [m89-verified]
#pragma unroll
    for (int i = 0; i < 4; i++) {
#pragma unroll
        for (int j = 0; j < 4; j++) {
            const int col = bn * 128 + wn + j * 16 + fr;
            float bv = 0.f;
            if constexpr (EPI != EPI_F32) bv = bias[col];
#pragma unroll
            for (int rg = 0; rg < 4; ++rg) {
                const int row = bm * 128 + wm + i * 16 + fg * 4 + rg;
                float v = acc[i][j][rg] + bv;
                if constexpr (EPI == EPI_BF16) {
                    obf[(size_t)row * N + col] = (bf16_t)v;
                } else if constexpr (EPI == EPI_GELU) {
                    v = 0.5f * v * (1.0f + erff(v * 0.70710678118f));
                    obf[(size_t)row * N + col] = (bf16_t)v;
                } else if constexpr (EPI == EPI_RES) {
                    resid[(size_t)row * CC + col] += v;
                } else {
                    of32[(size_t)row * N + col] = v;
                }
            }
        }
    }
}

// ---------------- GEMM (large-N): 256x256 tile, BK=32, 3-ring pipelined ----------------
// 8 waves (2M x 4N -> per-wave 128x64), dynamic LDS 96KB = 3 rings x (A 16KB + B 16KB).
// Schedule per K-tile T: counted vmcnt(4) (tile T+1's loads stay in flight) + ONE raw
// s_barrier, then 2 phases x 16 MFMA; stage tile T+2 into ring (T+2)%3 (free slot:
// ring-3 gives 2-K-tile hazard slack). Never drains vmcnt to 0 until the last tile (T4).
// Both-sides XOR swizzle (T2): LDS[row][c] holds G[row][c ^ sw(row)],
// sw(row) = (row&8?16:0)|(row&4?8:0) -> frag reads 2-way banked = free (m136).
// setprio(1) around MFMA clusters (T5).

template <int EPI>
__global__ __launch_bounds__(512, 1) void gemm8p(const bf16_t* __restrict__ A,
                                                 const bf16_t* __restrict__ Bw,
                                                 const float* __restrict__ bias,
                                                 bf16_t* __restrict__ obf,
                                                 int N, int K, int nbn) {
    extern __shared__ __align__(16) char smem[];
    bf16_t* ldsA = (bf16_t*)smem;            // [3][8192] elems
    bf16_t* ldsB = (bf16_t*)smem + 24576;    // [3][8192] elems
    const int nwg = gridDim.x;
    const int id  = blockIdx.x;
    const int swzid = (id & 7) * (nwg >> 3) + (id >> 3);
    const int bn = swzid % nbn, bm = swzid / nbn;
    const int t = threadIdx.x, wv = t >> 6, lane = t & 63;
    const int fr = lane & 15, fg = lane >> 4;
    const int wm2 = (wv >> 2) * 128, wn2 = (wv & 3) * 64;
    // frag-read swizzle depends only on fr bits 2,3 (row = ... + fr)
    const int swf = ((fr & 8) ? 16 : 0) | ((fr & 4) ? 8 : 0);
    const int rdA0 = (wm2 + fr) * 32 + ((fg * 8) ^ swf);   // + mi*512
    const int rdB0 = (wn2 + fr) * 32 + ((fg * 8) ^ swf);   // + ni*512
    // staging: issue i: row r = i*128 + wv*16 + (lane>>2), src col (lane&3)*8 ^ sw(r)
    const int rr0 = wv * 16 + (lane >> 2);
    const int sws = ((rr0 & 8) ? 16 : 0) | ((rr0 & 4) ? 8 : 0);
    const size_t gA0 = (size_t)(bm * 256 + rr0) * K + (((lane & 3) * 8) ^ sws);
    const size_t gB0 = (size_t)(bn * 256 + rr0) * K + (((lane & 3) * 8) ^ sws);
    const int ldsStage = wv * 512;                          // + i*4096 elems (lane*16B by HW)
    const int NT = K >> 5;

    f32x4 acc[8][4] = {};

    auto stA = [&](int T) {
        bf16_t* dst = ldsA + (T % 3) * 8192 + ldsStage;
        const bf16_t* s = A + gA0 + (size_t)T * 32;
        gload_lds16(s, dst);
        gload_lds16(s + (size_t)128 * K, dst + 4096);
    };
    auto stB = [&](int T) {
        bf16_t* dst = ldsB + (T % 3) * 8192 + ldsStage;
        const bf16_t* s = Bw + gB0 + (size_t)T * 32;
        gload_lds16(s, dst);
        gload_lds16(s + (size_t)128 * K, dst + 4096);
    };
    stA(0); stB(0); stA(1); stB(1);          // prologue: 8 loads in flight

    for (int T = 0; T < NT; ++T) {
        // ledger: issued = tiles [0..T+1]; wait until all of tile T landed.
        if (T == NT - 1) asm volatile("s_waitcnt vmcnt(0)" ::: "memory");
        else             asm volatile("s_waitcnt vmcnt(4)" ::: "memory");
        __builtin_amdgcn_s_barrier();        // publish tile T to all waves
        const bf16_t* As_ = ldsA + (T % 3) * 8192;
        const bf16_t* Bs_ = ldsB + (T % 3) * 8192;
        bf16x8 af[4], bf[4];
        // phase 1: mi 0..3, all ni
#pragma unroll
        for (int i = 0; i < 4; i++) af[i] = *(const bf16x8*)&As_[rdA0 + i * 512];
#pragma unroll
        for (int i = 0; i < 4; i++) bf[i] = *(const bf16x8*)&Bs_[rdB0 + i * 512];
        if (T + 2 < NT) stA(T + 2);
        __builtin_amdgcn_s_setprio(1);
#pragma unroll
        for (int mi = 0; mi < 4; mi++)
#pragma unroll
            for (int ni = 0; ni < 4; ni++)
                acc[mi][ni] = mfma16x16x32(af[mi], bf[ni], acc[mi][ni]);
        __builtin_amdgcn_s_setprio(0);
        // phase 2: mi 4..7 (B-frags reused in registers)
#pragma unroll
        for (int i = 0; i < 4; i++) af[i] = *(const bf16x8*)&As_[rdA0 + (4 + i) * 512];
        if (T + 2 < NT) stB(T + 2);
        __builtin_amdgcn_s_setprio(1);
#pragma unroll
        for (int mi = 0; mi < 4; mi++)
#pragma unroll
            for (int ni = 0; ni < 4; ni++)
                acc[4 + mi][ni] = mfma16x16x32(af[mi], bf[ni], acc[4 + mi][ni]);
        __builtin_amdgcn_s_setprio(0);
    }
    // epilogue: C/D layout col = fr, row = fg*4 + rg
#pragma unroll
    for (int mi = 0; mi < 8; mi++) {
#pragma unroll
        for (int ni = 0; ni < 4; ni++) {
            const int col = bn * 256 + wn2 + ni * 16 + fr;
            const float bv = bias[col];
#pragma unroll
            for (int rg = 0; rg < 4; rg++) {
                const int row = bm * 256 + wm2 + mi * 16 + fg * 4 + rg;
                float v = acc[mi][ni][rg] + bv;
                if constexpr (EPI == EPI_GELU)
                    v = 0.5f * v * (1.0f + erff(v * 0.70710678118f));
                obf[(size_t)row * N + col] = (bf16_t)v;
            }
        }
    }
}

// ---------------- Flash attention (v2: swapped QK^T, in-register P) ----------------
// qkv: [MR][3C] bf16 (q|k|v). Per block: one (b,h), 64 q-rows; 4 waves x 16 q-rows.
// KV tiles of 64. S^T = mfma(K, Q): lane fr = one q-column -> softmax needs only
// 2 shfls (xor 16/32), scalar m/lse. P redistributed to PV A-fragments entirely
// in-register (12 packed shfl_xor + selects) -- no P LDS round-trip. K staged
// swizzled row-major; V^T staged transposed (two-term XOR swizzle). Defer-max
// (T13), exp2 domain, next-tile preload (T14-lite). LDS 16KB.

__global__ __launch_bounds__(256, 4) void attn_k(const bf16_t* __restrict__ qkv,
                                                 bf16_t* __restrict__ y) {
    __shared__ __align__(16) bf16_t Ks[64 * 64];
    __shared__ __align__(16) bf16_t Vt[64 * 64];
    const int id = blockIdx.x;                    // 2048 blocks, %8==0
    const int swz = (id & 7) * 256 + (id >> 3);   // XCD swizzle: same bh -> same XCD
    const int qt = swz & 31, bh = swz >> 5;
    const int b = bh >> 4, h = bh & 15;
    const int t = threadIdx.x, w = t >> 6, l = t & 63;
    const int fr = l & 15, fg = l >> 4;
    const int hh = fg >> 1;                       // P-pack selector (0/1)
    const int q0 = qt * 64 + w * 16;
    const size_t bT = (size_t)b * TT;
    const float SCL = 0.125f * 1.44269504f;       // 1/sqrt(DH) * log2(e)

    bf16x8 qf[2];
    {
        const size_t qoff = (bT + q0 + fr) * 3072 + h * 64 + fg * 8;
        qf[0] = *(const bf16x8*)&qkv[qoff];
        qf[1] = *(const bf16x8*)&qkv[qoff + 32];
    }
    float mrun = -1e30f, lse = 0.f;               // per-lane, for q = fr (log2 units)
    f32x4 oacc[4] = {};                           // O[q=fg*4+rg][d=nd*16+fr]

    const int srow = t >> 2;            // 0..63: kv row staged by this thread
    const int c8a = (t & 3) * 8;        // elem offset in 64-wide row
    const int ksw = (srow & 7) << 4;
    char* KsB = (char*)Ks;
    char* VtB = (char*)Vt;

    s16x8 kr0, kr1, vr0, vr1;           // next-tile staging registers (T14)
    auto preload = [&](int kv0) {
        const size_t roff = (bT + kv0 + srow) * 3072 + h * 64;
        kr0 = *(const s16x8*)&qkv[roff + 1024 + c8a];
        kr1 = *(const s16x8*)&qkv[roff + 1024 + c8a + 32];
        vr0 = *(const s16x8*)&qkv[roff + 2048 + c8a];
        vr1 = *(const s16x8*)&qkv[roff + 2048 + c8a + 32];
    };
    preload(0);

    for (int kv0 = 0; kv0 < TT; kv0 += 64) {
        __syncthreads();                 // previous tile's LDS reads done
        // ---- regs -> LDS: K (swizzled row-major), V^T (transposed) ----
#pragma unroll
        for (int half = 0; half < 2; ++half) {
            const s16x8 kr = half ? kr1 : kr0;
            const s16x8 vr = half ? vr1 : vr0;
            const int c8 = c8a + half * 32;
            *(s16x8*)(KsB + srow * 128 + ((c8 * 2) ^ ksw)) = kr;
#pragma unroll
            for (int j = 0; j < 8; j++) {
                const int d = c8 + j;
                const int dsw = (((d & 7) ^ ((d >> 3) & 7)) << 4);
                *(short*)(VtB + d * 128 + ((srow * 2) ^ dsw)) = vr[j];
            }
        }
        __syncthreads();                 // LDS tile ready
        if (kv0 + 64 < TT) preload(kv0 + 64);   // issue next tile's loads early

        // ---- S^T = K Q^T: sacc[nt] rows k=16nt+fg*4+rg, col q=fr ----
        f32x4 sacc[4] = {};
#pragma unroll
        for (int nt = 0; nt < 4; nt++) {
            const int kr_ = nt * 16 + fr;
            const int sw = (kr_ & 7) << 4;
#pragma unroll
            for (int c = 0; c < 2; c++) {
                bf16x8 kf = *(const bf16x8*)(KsB + kr_ * 128 + ((c * 64 + fg * 16) ^ sw));
                sacc[nt] = mfma16x16x32(kf, qf[c], sacc[nt]);
            }
        }
        // ---- per-lane softmax over k (16 in-reg + cross-fg xor16/32) ----
        float tm = sacc[0][0];
#pragma unroll
        for (int nt = 0; nt < 4; nt++)
#pragma unroll
            for (int rg = 0; rg < 4; rg++) tm = fmaxf(tm, sacc[nt][rg]);
        tm = fmaxf(tm, __shfl_xor(tm, 16));
        tm = fmaxf(tm, __shfl_xor(tm, 32));
        tm *= SCL;
        if (!__all(tm - mrun <= 11.5f)) {        // T13 defer-max (~8/ln2)
            const float mn = fmaxf(mrun, tm);
            const float co = exp2f(mrun - mn);
            lse *= co; mrun = mn;
            const float cr0 = __shfl(co, fg * 4 + 0);
            const float cr1 = __shfl(co, fg * 4 + 1);
            const float cr2 = __shfl(co, fg * 4 + 2);
            const float cr3 = __shfl(co, fg * 4 + 3);
#pragma unroll
            for (int nd = 0; nd < 4; nd++) {
                oacc[nd][0] *= cr0; oacc[nd][1] *= cr1;
                oacc[nd][2] *= cr2; oacc[nd][3] *= cr3;
            }
        }
        // ---- P = exp2(S^T*SCL - m), packed (c0,c1) for redistribution ----
        const f32x4 sA0 = hh ? sacc[1] : sacc[0];     // nt = hh
        const f32x4 sA1 = hh ? sacc[3] : sacc[2];     // nt = 2+hh
        const f32x4 sB0 = hh ? sacc[0] : sacc[1];     // nt = hh^1
        const f32x4 sB1 = hh ? sacc[2] : sacc[3];     // nt = 2+(hh^1)
        float rs = 0.f;
        unsigned pkA[4], pkB[4];
#pragma unroll
        for (int rg = 0; rg < 4; rg++) {
            const float a0 = exp2f(sA0[rg] * SCL - mrun);
            const float a1 = exp2f(sA1[rg] * SCL - mrun);
            const float b0 = exp2f(sB0[rg] * SCL - mrun);
            const float b1 = exp2f(sB1[rg] * SCL - mrun);
            rs += (a0 + a1) + (b0 + b1);
            pkA[rg] = pack_bf16(a0, a1);
            pkB[rg] = pack_bf16(b0, b1);
        }
        rs += __shfl_xor(rs, 16);
        rs += __shfl_xor(rs, 32);
        lse += rs;
        // ---- redistribute P^T -> PV A-fragments ----
        unsigned s0pk[4], s1pk[4];
#pragma unroll
        for (int rg = 0; rg < 4; rg++) {
            const unsigned r16 = __shfl_xor(pkA[rg], 16);
            const unsigned r32 = __shfl_xor(pkB[rg], 32);
            const unsigned r48 = __shfl_xor(pkB[rg], 48);
            s0pk[rg] = (fg == 0) ? pkA[rg] : (fg == 1) ? r48 : (fg == 2) ? r32 : r16;
            s1pk[rg] = (fg == 0) ? r16 : (fg == 1) ? r32 : (fg == 2) ? r48 : pkA[rg];
        }
        u32x4 w0v, w1v;
        w0v[0] = (s0pk[0] & 0xFFFFu) | (s0pk[1] << 16);
        w0v[1] = (s0pk[2] & 0xFFFFu) | (s0pk[3] << 16);
        w0v[2] = (s1pk[0] & 0xFFFFu) | (s1pk[1] << 16);
        w0v[3] = (s1pk[2] & 0xFFFFu) | (s1pk[3] << 16);
        w1v[0] = (s0pk[0] >> 16) | (s0pk[1] & 0xFFFF0000u);
        w1v[1] = (s0pk[2] >> 16) | (s0pk[3] & 0xFFFF0000u);
        w1v[2] = (s1pk[0] >> 16) | (s1pk[1] & 0xFFFF0000u);
        w1v[3] = (s1pk[2] >> 16) | (s1pk[3] & 0xFFFF0000u);
        const bf16x8 paf0 = __builtin_bit_cast(bf16x8, w0v);
        const bf16x8 paf1 = __builtin_bit_cast(bf16x8, w1v);
        // ---- O += P V ----
#pragma unroll
        for (int nd = 0; nd < 4; nd++) {
            const int dr = nd * 16 + fr;
            const int dsw = (((dr & 7) ^ ((dr >> 3) & 7)) << 4);
            bf16x8 vf0 = *(const bf16x8*)(VtB + dr * 128 + ((fg * 16) ^ dsw));
            oacc[nd] = mfma16x16x32(paf0, vf0, oacc[nd]);
            bf16x8 vf1 = *(const bf16x8*)(VtB + dr * 128 + ((64 + fg * 16) ^ dsw));
            oacc[nd] = mfma16x16x32(paf1, vf1, oacc[nd]);
        }
    }
    // ---- normalize + write y ----
    const float inv = 1.f / lse;
    const float i0 = __shfl(inv, fg * 4 + 0);
    const float i1 = __shfl(inv, fg * 4 + 1);
    const float i2 = __shfl(inv, fg * 4 + 2);
    const float i3 = __shfl(inv, fg * 4 + 3);
#pragma unroll
    for (int nd = 0; nd < 4; nd++) {
        const size_t ro = (bT + q0 + fg * 4) * CC + h * 64 + nd * 16 + fr;
        y[ro]          = (bf16_t)(oacc[nd][0] * i0);
        y[ro + CC]     = (bf16_t)(oacc[nd][1] * i1);
        y[ro + 2 * CC] = (bf16_t)(oacc[nd][2] * i2);
        y[ro + 3 * CC] = (bf16_t)(oacc[nd][3] * i3);
    }
}

// ---------------- host ----------------

extern "C" void kernel_launch(void* const* d_in, const int* in_sizes, int n_in,
                              void* d_out, int out_size, void* d_ws, size_t ws_size,
                              hipStream_t stream) {
    (void)in_sizes; (void)n_in; (void)out_size; (void)ws_size;
    const float* seq  = (const float*)d_in[0];
    const float* pos  = (const float*)d_in[1];
    const float* Wq   = (const float*)d_in[2];
    const float* bq   = (const float*)d_in[3];
    const float* Wk   = (const float*)d_in[4];
    const float* bk   = (const float*)d_in[5];
    const float* Wv   = (const float*)d_in[6];
    const float* bv   = (const float*)d_in[7];
    const float* Wo   = (const float*)d_in[8];
    const float* bo   = (const float*)d_in[9];
    const float* ln1w = (const float*)d_in[10];
    const float* ln1b = (const float*)d_in[11];
    const float* ln2w = (const float*)d_in[12];
    const float* ln2b = (const float*)d_in[13];
    const float* W1   = (const float*)d_in[14];
    const float* b1   = (const float*)d_in[15];
    const float* W2   = (const float*)d_in[16];
    const float* b2   = (const float*)d_in[17];
    const float* lnfw = (const float*)d_in[18];
    const float* lnfb = (const float*)d_in[19];
    const float* Wh   = (const float*)d_in[20];
    float* out = (float*)d_out;

    // workspace layout (bytes) — total ~138 MB
    char* ws = (char*)d_ws;
    float*  x     = (float*)(ws + 0);            // 32 MB fp32 residual stream
    bf16_t* qkvb  = (bf16_t*)(ws + 33554432);    // 48 MB
    bf16_t* yb    = (bf16_t*)(ws + 83886080);    // 16 MB
    bf16_t* a1b   = (bf16_t*)(ws + 33554432);    // 64 MB, aliases qkv+y (dead by MLP1)
    bf16_t* hb    = (bf16_t*)(ws + 100663296);   // 16 MB (LN output)
    bf16_t* wqkvb = (bf16_t*)(ws + 117440512);   // 6 MB
    bf16_t* wob   = (bf16_t*)(ws + 123731968);   // 2 MB
    bf16_t* w1b   = (bf16_t*)(ws + 125829120);   // 8 MB
    bf16_t* w2b   = (bf16_t*)(ws + 134217728);   // 8 MB
    bf16_t* whb   = (bf16_t*)(ws + 142606336);   // 2 MB
    float*  bqkv  = (float*)(ws + 144703488);    // 12 KB

    hipFuncSetAttribute(reinterpret_cast<const void*>(gemm8p<EPI_BF16>),
                        hipFuncAttributeMaxDynamicSharedMemorySize, 98304);
    hipFuncSetAttribute(reinterpret_cast<const void*>(gemm8p<EPI_GELU>),
                        hipFuncAttributeMaxDynamicSharedMemorySize, 98304);

    f32_to_bf16_k<<<1024, 256, 0, stream>>>(Wh, whb, 262144);
    add_pos_k<<<8192, 256, 0, stream>>>(seq, pos, x);

    for (int l = 0; l < LAYERS; ++l) {
        const size_t wo_ = (size_t)l * CC * CC;
        const size_t w4_ = (size_t)l * 4 * CC * CC;
        convert_layer_k<<<12291, 256, 0, stream>>>(Wq + wo_, Wk + wo_, Wv + wo_, Wo + wo_,
                                                   W1 + w4_, W2 + w4_,
                                                   bq + l * CC, bk + l * CC, bv + l * CC,
                                                   wqkvb, wob, w1b, w2b, bqkv);

        ln_rows_k<<<2048, 256, 0, stream>>>(x, ln1w + l * CC, ln1b + l * CC, hb);
        gemm8p<EPI_BF16><<<384, 512, 98304, stream>>>(hb, wqkvb, bqkv, qkvb,
                                                      3072, 1024, 12);
        attn_k<<<2048, 256, 0, stream>>>(qkvb, yb);
        gemm_bt<EPI_RES><<<512, 256, 0, stream>>>(yb, wob, bo + l * CC, x,
                                                  nullptr, nullptr, 1024, 1024, 8);
        ln_rows_k<<<2048, 256, 0, stream>>>(x, ln2w + l * CC, ln2b + l * CC, hb);
        gemm8p<EPI_GELU><<<512, 512, 98304, stream>>>(hb, w1b, b1 + (size_t)l * 4 * CC,
                                                      a1b, 4096, 1024, 16);
        gemm_bt<EPI_RES><<<512, 256, 0, stream>>>(a1b, w2b, b2 + l * CC, x,
                                                  nullptr, nullptr, 1024, 4096, 8);
    }
    ln_rows_k<<<2048, 256, 0, stream>>>(x, lnfw, lnfb, hb);
    gemm_bt<EPI_F32><<<512, 256, 0, stream>>>(hb, whb, nullptr, nullptr,
                                              nullptr, out, 1024, 1024, 8);
}